// Round 1
// baseline (1186.875 us; speedup 1.0000x reference)
//
#include <hip/hip_runtime.h>

#define N_NODES 50000
#define E_EDGES 800000
#define FEAT    128
#define KORD    3
#define BN_EPS  1e-5f

// ---- ordered-uint encoding for float atomicMax (order-independent) ----
__device__ __forceinline__ unsigned f2o(float f) {
    unsigned u = __float_as_uint(f);
    return (u & 0x80000000u) ? ~u : (u | 0x80000000u);
}
__device__ __forceinline__ float o2f(unsigned u) {
    return (u & 0x80000000u) ? __uint_as_float(u ^ 0x80000000u)
                             : __uint_as_float(~u);
}

// ---- per-node precompute: g[n,3] = attW @ f[n];  xk[k,n,o] = sum_i f[n,i]*L[k,i,o]
__global__ void node_pre(const float* __restrict__ feat,
                         const float* __restrict__ linear,
                         const float* __restrict__ attW,
                         float* __restrict__ xk,
                         float* __restrict__ g) {
    const int n = blockIdx.x;
    const int o = threadIdx.x;           // 128 threads
    __shared__ float sf[FEAT];
    sf[o] = feat[n * FEAT + o];
    __syncthreads();

    #pragma unroll
    for (int k = 0; k < KORD; ++k) {
        float acc = 0.f;
        #pragma unroll 8
        for (int i = 0; i < FEAT; ++i)
            acc = fmaf(sf[i], linear[(k * FEAT + i) * FEAT + o], acc);
        xk[(k * N_NODES + n) * FEAT + o] = acc;
    }
    if (o < 3) {
        float s = 0.f;
        #pragma unroll 8
        for (int i = 0; i < FEAT; ++i)
            s = fmaf(attW[o * FEAT + i], sf[i], s);
        g[n * 3 + o] = s;
    }
}

// ---- per-edge attention logits + inverse distance; segment max into m_u ----
__global__ void edge_att(const float* __restrict__ coords,
                         const float* __restrict__ g,
                         const int* __restrict__ src,
                         const int* __restrict__ dst,
                         float* __restrict__ ebuf,   // att
                         float* __restrict__ invd,
                         unsigned* __restrict__ m_u) {
    const int e = blockIdx.x * blockDim.x + threadIdx.x;
    if (e >= E_EDGES) return;
    const int s = src[e], d = dst[e];
    const float dx = coords[s * 3 + 0] - coords[d * 3 + 0];
    const float dy = coords[s * 3 + 1] - coords[d * 3 + 1];
    const float dz = coords[s * 3 + 2] - coords[d * 3 + 2];
    const float a = dx * g[s * 3 + 0] + dy * g[s * 3 + 1] + dz * g[s * 3 + 2];
    ebuf[e] = a;
    invd[e] = 1.f / (dx * dx + dy * dy + dz * dz + 1.f);
    atomicMax(m_u + d, f2o(a));
}

// ---- ex = exp(att - m[dst]); denom[dst] += ex  (in-place att -> ex) ----
__global__ void edge_exp(const int* __restrict__ dst,
                         const unsigned* __restrict__ m_u,
                         float* __restrict__ ebuf,
                         float* __restrict__ denom) {
    const int e = blockIdx.x * blockDim.x + threadIdx.x;
    if (e >= E_EDGES) return;
    const int d = dst[e];
    const float ex = expf(ebuf[e] - o2f(m_u[d]));
    ebuf[e] = ex;
    atomicAdd(denom + d, ex);
}

// ---- w = ex/denom * invdist  (in-place ex -> w) ----
__global__ void edge_w(const int* __restrict__ dst,
                       const float* __restrict__ denom,
                       const float* __restrict__ invd,
                       float* __restrict__ ebuf) {
    const int e = blockIdx.x * blockDim.x + threadIdx.x;
    if (e >= E_EDGES) return;
    const float d = denom[dst[e]];
    ebuf[e] = ebuf[e] / (d > 0.f ? d : 1.f) * invd[e];
}

// ---- h[dst,:] += w[e] * xk[order[e], src[e], :]  (f32 atomics) ----
__global__ void scatter(const float* __restrict__ ebuf,
                        const float* __restrict__ xk,
                        const int* __restrict__ src,
                        const int* __restrict__ dst,
                        const int* __restrict__ order,
                        float* __restrict__ h) {
    const int idx = blockIdx.x * blockDim.x + threadIdx.x;   // < E*128 = 102.4M
    const int e = idx >> 7;
    const int o = idx & 127;
    const float v = ebuf[e] * xk[(order[e] * N_NODES + src[e]) * FEAT + o];
    atomicAdd(h + dst[e] * FEAT + o, v);
}

// ---- y = relu(h @ W^T + b) -> out (pre-BN) ----
__global__ void mlp(const float* __restrict__ h,
                    const float* __restrict__ W,
                    const float* __restrict__ b,
                    float* __restrict__ y) {
    const int n = blockIdx.x;
    const int o = threadIdx.x;
    __shared__ float sh[FEAT];
    sh[o] = h[n * FEAT + o];
    __syncthreads();
    float acc = b[o];
    #pragma unroll 8
    for (int i = 0; i < FEAT; ++i)
        acc = fmaf(sh[i], W[o * FEAT + i], acc);
    y[n * FEAT + o] = fmaxf(acc, 0.f);
}

// ---- per-column sum / sumsq over N rows ----
__global__ void stats(const float* __restrict__ y,
                      float* __restrict__ sbuf) {   // [0:128)=sum [128:256)=sumsq
    const int o = threadIdx.x;
    float s = 0.f, s2 = 0.f;
    for (int n = blockIdx.x; n < N_NODES; n += gridDim.x) {
        const float v = y[n * FEAT + o];
        s += v;
        s2 = fmaf(v, v, s2);
    }
    atomicAdd(sbuf + o, s);
    atomicAdd(sbuf + FEAT + o, s2);
}

// ---- mean/var -> scale/shift ----
__global__ void finalize(const float* __restrict__ sbuf,
                         const float* __restrict__ gamma,
                         const float* __restrict__ beta,
                         float* __restrict__ ss) {   // [0:128)=scale [128:256)=shift
    const int o = threadIdx.x;
    const float mean = sbuf[o] / (float)N_NODES;
    const float var  = sbuf[FEAT + o] / (float)N_NODES - mean * mean;
    const float sc   = gamma[o] * rsqrtf(var + BN_EPS);
    ss[o] = sc;
    ss[FEAT + o] = beta[o] - mean * sc;
}

// ---- out = out*scale + shift (in place) ----
__global__ void normalize(float* __restrict__ y,
                          const float* __restrict__ ss) {
    const int idx = blockIdx.x * blockDim.x + threadIdx.x;   // N*128 threads
    const int o = idx & 127;
    y[idx] = fmaf(y[idx], ss[o], ss[FEAT + o]);
}

extern "C" void kernel_launch(void* const* d_in, const int* in_sizes, int n_in,
                              void* d_out, int out_size, void* d_ws, size_t ws_size,
                              hipStream_t stream) {
    const float* feature = (const float*)d_in[0];
    const float* coords  = (const float*)d_in[1];
    const int*   src     = (const int*)d_in[2];
    const int*   dst     = (const int*)d_in[3];
    const int*   order   = (const int*)d_in[4];
    const float* linear  = (const float*)d_in[5];
    const float* attW    = (const float*)d_in[6];
    const float* mlp_w   = (const float*)d_in[7];
    const float* mlp_b   = (const float*)d_in[8];
    const float* gamma   = (const float*)d_in[9];
    const float* beta    = (const float*)d_in[10];
    float* out = (float*)d_out;

    // workspace layout (all 256B aligned by construction)
    char* p = (char*)d_ws;
    float*    xk    = (float*)p;    p += (size_t)KORD * N_NODES * FEAT * 4;  // 76.8 MB
    float*    ebuf  = (float*)p;    p += (size_t)E_EDGES * 4;                //  3.2 MB
    float*    invd  = (float*)p;    p += (size_t)E_EDGES * 4;                //  3.2 MB
    unsigned* m_u   = (unsigned*)p; p += (size_t)N_NODES * 4;                //  0.2 MB
    float*    denom = (float*)p;    p += (size_t)N_NODES * 4;                //  0.2 MB
    float*    h     = (float*)p;    p += (size_t)N_NODES * FEAT * 4;         // 25.6 MB
    float*    g     = (float*)p;    p += (size_t)N_NODES * 3 * 4;            //  0.6 MB
    float*    sbuf  = (float*)p;    p += 256 * 4;                            // stats
    float*    ss    = (float*)p;    p += 256 * 4;                            // scale/shift

    hipMemsetAsync(m_u,   0, (size_t)N_NODES * 4, stream);
    hipMemsetAsync(denom, 0, (size_t)N_NODES * 4, stream);
    hipMemsetAsync(h,     0, (size_t)N_NODES * FEAT * 4, stream);
    hipMemsetAsync(sbuf,  0, 256 * 4, stream);

    node_pre<<<N_NODES, FEAT, 0, stream>>>(feature, linear, attW, xk, g);

    const int EB = (E_EDGES + 255) / 256;
    edge_att<<<EB, 256, 0, stream>>>(coords, g, src, dst, ebuf, invd, m_u);
    edge_exp<<<EB, 256, 0, stream>>>(dst, m_u, ebuf, denom);
    edge_w  <<<EB, 256, 0, stream>>>(dst, denom, invd, ebuf);

    scatter<<<(E_EDGES * FEAT) / 256, 256, 0, stream>>>(ebuf, xk, src, dst, order, h);

    mlp<<<N_NODES, FEAT, 0, stream>>>(h, mlp_w, mlp_b, out);
    stats<<<256, FEAT, 0, stream>>>(out, sbuf);
    finalize<<<1, FEAT, 0, stream>>>(sbuf, gamma, beta, ss);
    normalize<<<(N_NODES * FEAT) / 256, 256, 0, stream>>>(out, ss);
}